// Round 7
// baseline (1965.898 us; speedup 1.0000x reference)
//
#include <hip/hip_runtime.h>

#define NB 4
#define NS 2048
#define ND 768
#define NH 12
#define NDH 64
#define NM (NB * NS)   // 8192

typedef __attribute__((ext_vector_type(8))) unsigned short u16x8;

__device__ __forceinline__ unsigned short f2h(float f) {
    _Float16 h = (_Float16)f;
    return __builtin_bit_cast(unsigned short, h);
}
__device__ __forceinline__ float h2f(unsigned short u) {
    return (float)__builtin_bit_cast(_Float16, u);
}

// ---------------------------------------------------------------------------
// Kernel 1 (unchanged from R4): VALU fp32 QKV GEMM.
// C[m][n] = sum_k x[m][k] * W[n][k] + bias[n]; head-split [B,H,S,DH] fp16 ws.
// ---------------------------------------------------------------------------
__global__ __launch_bounds__(256)
void qkv_gemm_valu(const float* __restrict__ x,
                   const float* __restrict__ wq,
                   const float* __restrict__ wk,
                   const float* __restrict__ wv,
                   const float* __restrict__ bq,
                   const float* __restrict__ bk,
                   const float* __restrict__ bv,
                   unsigned short* __restrict__ qkv)
{
    const int z = blockIdx.z;
    const float* W    = (z == 0) ? wq : (z == 1) ? wk : wv;
    const float* bias = (z == 0) ? bq : (z == 1) ? bk : bv;
    unsigned short* out = qkv + (size_t)z * NM * ND;

    const int m0 = blockIdx.x * 64;
    const int n0 = blockIdx.y * 64;
    const int tid = threadIdx.x;
    const int tx = tid & 15;
    const int ty = tid >> 4;

    __shared__ float As[64][17];
    __shared__ float Bs[64][17];

    float acc[4][4];
#pragma unroll
    for (int i = 0; i < 4; ++i)
#pragma unroll
        for (int j = 0; j < 4; ++j) acc[i][j] = 0.f;

    const int sr = tid >> 2;
    const int sc = (tid & 3) * 4;

    for (int kt = 0; kt < ND / 16; ++kt) {
        const int k0 = kt * 16;
        __syncthreads();
        {
            float4 av = *(const float4*)&x[(size_t)(m0 + sr) * ND + k0 + sc];
            float4 bv2 = *(const float4*)&W[(size_t)(n0 + sr) * ND + k0 + sc];
            As[sr][sc + 0] = av.x; As[sr][sc + 1] = av.y;
            As[sr][sc + 2] = av.z; As[sr][sc + 3] = av.w;
            Bs[sr][sc + 0] = bv2.x; Bs[sr][sc + 1] = bv2.y;
            Bs[sr][sc + 2] = bv2.z; Bs[sr][sc + 3] = bv2.w;
        }
        __syncthreads();

#pragma unroll
        for (int kk = 0; kk < 16; ++kk) {
            float a[4], b[4];
#pragma unroll
            for (int i = 0; i < 4; ++i) a[i] = As[ty * 4 + i][kk];
#pragma unroll
            for (int j = 0; j < 4; ++j) b[j] = Bs[tx * 4 + j][kk];
#pragma unroll
            for (int i = 0; i < 4; ++i)
#pragma unroll
                for (int j = 0; j < 4; ++j)
                    acc[i][j] = fmaf(a[i], b[j], acc[i][j]);
        }
    }

#pragma unroll
    for (int j = 0; j < 4; ++j) {
        const int n = n0 + tx * 4 + j;
        const float bval = bias[n];
        const int hh = n >> 6, d = n & 63;
#pragma unroll
        for (int i = 0; i < 4; ++i) {
            const int m = m0 + ty * 4 + i;
            const int bi = m >> 11, s = m & (NS - 1);
            out[(((size_t)(bi * NH + hh)) * NS + s) * NDH + d] =
                f2h(acc[i][j] + bval);
        }
    }
}

// ---------------------------------------------------------------------------
// Kernel 2: VALU flash attention (R4 verbatim) — ONLY CHANGE: fp32 output.
// ---------------------------------------------------------------------------
#define ATS 32

__global__ __launch_bounds__(256)
void attn_valu(const unsigned short* __restrict__ qh,
               const unsigned short* __restrict__ kh,
               const unsigned short* __restrict__ vh,
               float* __restrict__ out)              // <-- fp32 out
{
    const int bh = blockIdx.y;
    const int bb = bh / NH, hh = bh % NH;
    const int qr = blockIdx.x * 256 + threadIdx.x;

    const unsigned short* qb = qh + (size_t)bh * NS * NDH;
    const unsigned short* kb = kh + (size_t)bh * NS * NDH;
    const unsigned short* vb = vh + (size_t)bh * NS * NDH;

    float qf[NDH];
#pragma unroll
    for (int c = 0; c < 8; ++c) {
        u16x8 t = *(const u16x8*)&qb[(size_t)qr * NDH + c * 8];
#pragma unroll
        for (int j = 0; j < 8; ++j) qf[c * 8 + j] = h2f(t[j]);
    }

    const float c2 = 0.18033688011112042f;  // log2(e) / sqrt(64)
    float m = -__builtin_inff(), l = 0.f;
    float o[NDH];
#pragma unroll
    for (int j = 0; j < NDH; ++j) o[j] = 0.f;

    __shared__ float Ks2[ATS][NDH];
    __shared__ float Vs2[ATS][NDH];

    const int srow = (threadIdx.x * 8) >> 6;
    const int scol = (threadIdx.x * 8) & 63;

    for (int kt = 0; kt < NS / ATS; ++kt) {
        const int kv0 = kt * ATS;
        __syncthreads();
        {
            u16x8 tk = *(const u16x8*)&kb[(size_t)(kv0 + srow) * NDH + scol];
            u16x8 tv = *(const u16x8*)&vb[(size_t)(kv0 + srow) * NDH + scol];
#pragma unroll
            for (int j = 0; j < 8; ++j) {
                Ks2[srow][scol + j] = h2f(tk[j]);
                Vs2[srow][scol + j] = h2f(tv[j]);
            }
        }
        __syncthreads();

#pragma unroll 4
        for (int kv = 0; kv < ATS; ++kv) {
            float s = 0.f;
#pragma unroll
            for (int j = 0; j < NDH; ++j) s = fmaf(qf[j], Ks2[kv][j], s);
            const float s2 = s * c2;
            const float mn = fmaxf(m, s2);
            const float al = exp2f(m - mn);
            const float pl = exp2f(s2 - mn);
            l = l * al + pl;
            m = mn;
#pragma unroll
            for (int j = 0; j < NDH; ++j)
                o[j] = fmaf(pl, Vs2[kv][j], o[j] * al);
        }
    }

    const float inv = 1.f / l;
#pragma unroll
    for (int j = 0; j < NDH; ++j)
        out[((size_t)(bb * NS + qr)) * ND + hh * NDH + j] = o[j] * inv;  // fp32 store
}

// ---------------------------------------------------------------------------
extern "C" void kernel_launch(void* const* d_in, const int* in_sizes, int n_in,
                              void* d_out, int out_size, void* d_ws, size_t ws_size,
                              hipStream_t stream)
{
    const float* x  = (const float*)d_in[0];
    const float* Wq = (const float*)d_in[1];
    const float* bq = (const float*)d_in[2];
    const float* Wk = (const float*)d_in[3];
    const float* bk = (const float*)d_in[4];
    const float* Wv = (const float*)d_in[5];
    const float* bv = (const float*)d_in[6];

    unsigned short* qkv = (unsigned short*)d_ws;   // 3*NM*ND fp16 = 37.7 MB
    unsigned short* qhp = qkv;
    unsigned short* khp = qkv + (size_t)NM * ND;
    unsigned short* vhp = qkv + (size_t)2 * NM * ND;

    qkv_gemm_valu<<<dim3(NM / 64, ND / 64, 3), 256, 0, stream>>>(
        x, Wq, Wk, Wv, bq, bk, bv, qkv);

    attn_valu<<<dim3(NS / 256, NB * NH), 256, 0, stream>>>(
        qhp, khp, vhp, (float*)d_out);
}

// Round 8
// 436.660 us; speedup vs baseline: 4.5021x; 4.5021x over previous
//
#include <hip/hip_runtime.h>

#define NB 4
#define NS 2048
#define ND 768
#define NH 12
#define NDH 64
#define NM (NB * NS)   // 8192

typedef __attribute__((ext_vector_type(8))) _Float16 f16x8;
typedef __attribute__((ext_vector_type(8))) unsigned short u16x8;
typedef __attribute__((ext_vector_type(4))) float f32x4;

__device__ __forceinline__ unsigned short f2h(float f) {
    _Float16 h = (_Float16)f;
    return __builtin_bit_cast(unsigned short, h);
}
__device__ __forceinline__ f16x8 ldf16x8(const unsigned short* p) {
    return __builtin_bit_cast(f16x8, *(const u16x8*)p);
}

// ---------------------------------------------------------------------------
// Kernel 1: QKV projection GEMM, MFMA f16 (R2 structure, cross-validated vs
// VALU ground truth in R3).  fp32->fp16 conversion folded into LDS staging.
// C[m][n] = sum_k x[m][k]*W[n][k] + bias[n]; head-split [B,H,S,DH] fp16 ws.
// 128x128 tile, BK=32, 4 waves (2x2 of 64x64), mfma_f32_16x16x32_f16.
// ---------------------------------------------------------------------------
#define GLD 56   // LDS row stride (elems): 2-way-free frag reads (m136)

__global__ __launch_bounds__(256)
void qkv_gemm(const float* __restrict__ x,
              const float* __restrict__ wq,
              const float* __restrict__ wk,
              const float* __restrict__ wv,
              const float* __restrict__ bq,
              const float* __restrict__ bk,
              const float* __restrict__ bv,
              unsigned short* __restrict__ qkv)
{
    const int z = blockIdx.z;
    const float* W    = (z == 0) ? wq : (z == 1) ? wk : wv;
    const float* bias = (z == 0) ? bq : (z == 1) ? bk : bv;
    unsigned short* out = qkv + (size_t)z * NM * ND;

    const int m0 = blockIdx.x * 128;
    const int n0 = blockIdx.y * 128;
    const int tid = threadIdx.x;
    const int lane = tid & 63, wave = tid >> 6;
    const int quad = lane >> 4, l16 = lane & 15;
    const int wm = (wave >> 1) * 64, wn = (wave & 1) * 64;

    __shared__ __align__(16) unsigned short As[128 * GLD];
    __shared__ __align__(16) unsigned short Bs[128 * GLD];

    const f32x4 fz = {0.f, 0.f, 0.f, 0.f};
    f32x4 acc[4][4];
#pragma unroll
    for (int i = 0; i < 4; ++i)
#pragma unroll
        for (int j = 0; j < 4; ++j) acc[i][j] = fz;

    const int srow = tid >> 2;           // 0..63
    const int scb = (tid & 3) * 8;       // 0,8,16,24

    for (int kt = 0; kt < ND / 32; ++kt) {
        const int k0 = kt * 32;
        __syncthreads();
#pragma unroll
        for (int i = 0; i < 2; ++i) {
            const int row = srow + i * 64;
            const float4 a0 = *(const float4*)&x[(size_t)(m0 + row) * ND + k0 + scb];
            const float4 a1 = *(const float4*)&x[(size_t)(m0 + row) * ND + k0 + scb + 4];
            const float4 b0 = *(const float4*)&W[(size_t)(n0 + row) * ND + k0 + scb];
            const float4 b1 = *(const float4*)&W[(size_t)(n0 + row) * ND + k0 + scb + 4];
            u16x8 ra, rb;
            ra[0] = f2h(a0.x); ra[1] = f2h(a0.y); ra[2] = f2h(a0.z); ra[3] = f2h(a0.w);
            ra[4] = f2h(a1.x); ra[5] = f2h(a1.y); ra[6] = f2h(a1.z); ra[7] = f2h(a1.w);
            rb[0] = f2h(b0.x); rb[1] = f2h(b0.y); rb[2] = f2h(b0.z); rb[3] = f2h(b0.w);
            rb[4] = f2h(b1.x); rb[5] = f2h(b1.y); rb[6] = f2h(b1.z); rb[7] = f2h(b1.w);
            *(u16x8*)&As[row * GLD + scb] = ra;
            *(u16x8*)&Bs[row * GLD + scb] = rb;
        }
        __syncthreads();

        f16x8 af[4], bf_[4];
#pragma unroll
        for (int mi = 0; mi < 4; ++mi)
            af[mi] = ldf16x8(&As[(wm + mi * 16 + l16) * GLD + quad * 8]);
#pragma unroll
        for (int ni = 0; ni < 4; ++ni)
            bf_[ni] = ldf16x8(&Bs[(wn + ni * 16 + l16) * GLD + quad * 8]);
#pragma unroll
        for (int mi = 0; mi < 4; ++mi)
#pragma unroll
            for (int ni = 0; ni < 4; ++ni)
                acc[mi][ni] = __builtin_amdgcn_mfma_f32_16x16x32_f16(
                    af[mi], bf_[ni], acc[mi][ni], 0, 0, 0);
    }

    // epilogue: C/D layout col=lane&15, row=quad*4+reg (verified m89/m91)
#pragma unroll
    for (int ni = 0; ni < 4; ++ni) {
        const int n = n0 + wn + ni * 16 + l16;
        const float bval = bias[n];
        const int hh = n >> 6, d = n & 63;
#pragma unroll
        for (int mi = 0; mi < 4; ++mi) {
#pragma unroll
            for (int r = 0; r < 4; ++r) {
                const int m = m0 + wm + mi * 16 + quad * 4 + r;
                const int bi = m >> 11, s = m & (NS - 1);
                out[(((size_t)(bi * NH + hh)) * NS + s) * NDH + d] =
                    f2h(acc[mi][ni][r] + bval);
            }
        }
    }
}

// ---------------------------------------------------------------------------
// Kernel 2: MFMA flash attention (R2 structure; only change: fp32 out-store).
// 1 block = 128 Q rows of one (b,h); 32 rows/wave.  KV tiles of 64.
// ---------------------------------------------------------------------------
#define ALD 72

__global__ __launch_bounds__(256)
void attn_kernel(const unsigned short* __restrict__ qh,
                 const unsigned short* __restrict__ kh,
                 const unsigned short* __restrict__ vh,
                 float* __restrict__ out)             // fp32 out (THE fix)
{
    const int bh = blockIdx.y;
    const int bb = bh / NH, hh = bh % NH;
    const int tid = threadIdx.x;
    const int lane = tid & 63, wave = tid >> 6;
    const int quad = lane >> 4, l16 = lane & 15;
    const int q0 = blockIdx.x * 128 + wave * 32;

    __shared__ __align__(16) unsigned short Ks[64 * ALD];
    __shared__ __align__(16) unsigned short VTs[64 * ALD];   // [d][kv]
    __shared__ __align__(16) unsigned short Ps[4][32 * ALD]; // per-wave P strip

    const unsigned short* qb = qh + (size_t)bh * NS * NDH;
    const unsigned short* kb = kh + (size_t)bh * NS * NDH;
    const unsigned short* vb = vh + (size_t)bh * NS * NDH;

    f16x8 aq[2][2];
#pragma unroll
    for (int mt = 0; mt < 2; ++mt)
#pragma unroll
        for (int kk = 0; kk < 2; ++kk)
            aq[mt][kk] = ldf16x8(
                &qb[(size_t)(q0 + mt * 16 + l16) * NDH + kk * 32 + quad * 8]);

    const float c2 = 0.18033688011112042f;  // log2(e) / sqrt(64)

    const f32x4 fz = {0.f, 0.f, 0.f, 0.f};
    f32x4 o[2][4];
    float m2[2][4], lsum[2][4];
#pragma unroll
    for (int mt = 0; mt < 2; ++mt) {
#pragma unroll
        for (int nt = 0; nt < 4; ++nt) o[mt][nt] = fz;
#pragma unroll
        for (int r = 0; r < 4; ++r) { m2[mt][r] = -__builtin_inff(); lsum[mt][r] = 0.f; }
    }

    const int kcb = (tid & 7) * 8;

    for (int kt = 0; kt < NS / 64; ++kt) {
        const int kv0 = kt * 64;
        __syncthreads();
#pragma unroll
        for (int i = 0; i < 2; ++i) {
            int row = (tid >> 3) + i * 32;
            *(u16x8*)&Ks[row * ALD + kcb] =
                *(const u16x8*)&kb[(size_t)(kv0 + row) * NDH + kcb];
        }
#pragma unroll
        for (int i = 0; i < 2; ++i) {
            const int vrow = lane;
            const int cb = (wave + i * 4) * 8;
            u16x8 vv = *(const u16x8*)&vb[(size_t)(kv0 + vrow) * NDH + cb];
#pragma unroll
            for (int j = 0; j < 8; ++j)
                VTs[(cb + j) * ALD + vrow] = vv[j];
        }
        __syncthreads();

        f16x8 bkf[4][2];
#pragma unroll
        for (int nt = 0; nt < 4; ++nt)
#pragma unroll
            for (int kk = 0; kk < 2; ++kk)
                bkf[nt][kk] = ldf16x8(&Ks[(nt * 16 + l16) * ALD + kk * 32 + quad * 8]);

        f32x4 s[2][4];
#pragma unroll
        for (int mt = 0; mt < 2; ++mt)
#pragma unroll
            for (int nt = 0; nt < 4; ++nt) {
                s[mt][nt] = fz;
#pragma unroll
                for (int kk = 0; kk < 2; ++kk)
                    s[mt][nt] = __builtin_amdgcn_mfma_f32_16x16x32_f16(
                        aq[mt][kk], bkf[nt][kk], s[mt][nt], 0, 0, 0);
            }

#pragma unroll
        for (int mt = 0; mt < 2; ++mt) {
            float rm[4];
#pragma unroll
            for (int r = 0; r < 4; ++r)
                rm[r] = fmaxf(fmaxf(s[mt][0][r], s[mt][1][r]),
                              fmaxf(s[mt][2][r], s[mt][3][r]));
#pragma unroll
            for (int off = 1; off < 16; off <<= 1)
#pragma unroll
                for (int r = 0; r < 4; ++r)
                    rm[r] = fmaxf(rm[r], __shfl_xor(rm[r], off, 64));
            float al[4];
#pragma unroll
            for (int r = 0; r < 4; ++r) {
                float mn = fmaxf(m2[mt][r], rm[r] * c2);
                al[r] = exp2f(m2[mt][r] - mn);
                m2[mt][r] = mn;
            }
            float p[4][4], rs[4];
#pragma unroll
            for (int nt = 0; nt < 4; ++nt)
#pragma unroll
                for (int r = 0; r < 4; ++r)
                    p[nt][r] = exp2f(fmaf(s[mt][nt][r], c2, -m2[mt][r]));
#pragma unroll
            for (int r = 0; r < 4; ++r)
                rs[r] = (p[0][r] + p[1][r]) + (p[2][r] + p[3][r]);
#pragma unroll
            for (int off = 1; off < 16; off <<= 1)
#pragma unroll
                for (int r = 0; r < 4; ++r)
                    rs[r] += __shfl_xor(rs[r], off, 64);
#pragma unroll
            for (int r = 0; r < 4; ++r)
                lsum[mt][r] = lsum[mt][r] * al[r] + rs[r];
#pragma unroll
            for (int nt = 0; nt < 4; ++nt)
#pragma unroll
                for (int r = 0; r < 4; ++r)
                    o[mt][nt][r] *= al[r];
#pragma unroll
            for (int nt = 0; nt < 4; ++nt)
#pragma unroll
                for (int r = 0; r < 4; ++r)
                    Ps[wave][(mt * 16 + quad * 4 + r) * ALD + nt * 16 + l16] =
                        f2h(p[nt][r]);
        }

        f16x8 apf[2][2], bvf[4][2];
#pragma unroll
        for (int mt = 0; mt < 2; ++mt)
#pragma unroll
            for (int kk = 0; kk < 2; ++kk)
                apf[mt][kk] = ldf16x8(&Ps[wave][(mt * 16 + l16) * ALD + kk * 32 + quad * 8]);
#pragma unroll
        for (int nt = 0; nt < 4; ++nt)
#pragma unroll
            for (int kk = 0; kk < 2; ++kk)
                bvf[nt][kk] = ldf16x8(&VTs[(nt * 16 + l16) * ALD + kk * 32 + quad * 8]);
#pragma unroll
        for (int mt = 0; mt < 2; ++mt)
#pragma unroll
            for (int nt = 0; nt < 4; ++nt)
#pragma unroll
                for (int kk = 0; kk < 2; ++kk)
                    o[mt][nt] = __builtin_amdgcn_mfma_f32_16x16x32_f16(
                        apf[mt][kk], bvf[nt][kk], o[mt][nt], 0, 0, 0);
    }

    // epilogue: merge heads -> [B,S,H*DH], fp32 output
#pragma unroll
    for (int mt = 0; mt < 2; ++mt)
#pragma unroll
        for (int nt = 0; nt < 4; ++nt)
#pragma unroll
            for (int r = 0; r < 4; ++r) {
                const int srow = q0 + mt * 16 + quad * 4 + r;
                const int d = nt * 16 + l16;
                out[((size_t)(bb * NS + srow)) * ND + hh * NDH + d] =
                    o[mt][nt][r] / lsum[mt][r];
            }
}

// ---------------------------------------------------------------------------
extern "C" void kernel_launch(void* const* d_in, const int* in_sizes, int n_in,
                              void* d_out, int out_size, void* d_ws, size_t ws_size,
                              hipStream_t stream)
{
    const float* x  = (const float*)d_in[0];
    const float* Wq = (const float*)d_in[1];
    const float* bq = (const float*)d_in[2];
    const float* Wk = (const float*)d_in[3];
    const float* bk = (const float*)d_in[4];
    const float* Wv = (const float*)d_in[5];
    const float* bv = (const float*)d_in[6];

    unsigned short* qkv = (unsigned short*)d_ws;   // 3*NM*ND fp16 = 37.7 MB
    unsigned short* qhp = qkv;
    unsigned short* khp = qkv + (size_t)NM * ND;
    unsigned short* vhp = qkv + (size_t)2 * NM * ND;

    qkv_gemm<<<dim3(NM / 128, ND / 128, 3), 256, 0, stream>>>(
        x, Wq, Wk, Wv, bq, bk, bv, qkv);

    attn_kernel<<<dim3(NS / 128, NB * NH), 256, 0, stream>>>(
        qhp, khp, vhp, (float*)d_out);
}

// Round 9
// 282.180 us; speedup vs baseline: 6.9668x; 1.5475x over previous
//
#include <hip/hip_runtime.h>

#define NB 4
#define NS 2048
#define ND 768
#define NH 12
#define NDH 64
#define NM (NB * NS)   // 8192

typedef __attribute__((ext_vector_type(8))) _Float16 f16x8;
typedef __attribute__((ext_vector_type(4))) _Float16 f16x4;
typedef __attribute__((ext_vector_type(8))) unsigned short u16x8;
typedef __attribute__((ext_vector_type(4))) unsigned short u16x4;
typedef __attribute__((ext_vector_type(4))) float f32x4;

__device__ __forceinline__ unsigned short f2h(float f) {
    _Float16 h = (_Float16)f;
    return __builtin_bit_cast(unsigned short, h);
}
__device__ __forceinline__ f16x8 ldf16x8(const unsigned short* p) {
    return __builtin_bit_cast(f16x8, *(const u16x8*)p);
}
__device__ __forceinline__ f16x4 ldf16x4(const unsigned short* p) {
    return __builtin_bit_cast(f16x4, *(const u16x4*)p);
}

// ---------------------------------------------------------------------------
// Kernel 0: fp32 -> fp16 conversion of x, Wq, Wk, Wv into ws (xh | wh[3])
// ---------------------------------------------------------------------------
__global__ __launch_bounds__(256)
void conv_f32_to_f16(const float* __restrict__ x,
                     const float* __restrict__ wq,
                     const float* __restrict__ wk,
                     const float* __restrict__ wv,
                     unsigned short* __restrict__ dst)
{
    const int CX = (NM * ND) / 8;   // 786432
    const int CW = (ND * ND) / 8;   // 73728
    int c = blockIdx.x * 256 + threadIdx.x;
    const float* src;
    int base;
    if (c < CX)               { src = x;  base = 0; }
    else if (c < CX + CW)     { src = wq; base = CX; }
    else if (c < CX + 2 * CW) { src = wk; base = CX + CW; }
    else                      { src = wv; base = CX + 2 * CW; }
    const float4* p = (const float4*)&src[(size_t)(c - base) * 8];
    float4 a = p[0], b = p[1];
    u16x8 r;
    r[0] = f2h(a.x); r[1] = f2h(a.y); r[2] = f2h(a.z); r[3] = f2h(a.w);
    r[4] = f2h(b.x); r[5] = f2h(b.y); r[6] = f2h(b.z); r[7] = f2h(b.w);
    *(u16x8*)&dst[(size_t)c * 8] = r;
}

// ---------------------------------------------------------------------------
// Kernel 1: QKV GEMM, fp16 in (R2-proven structure).  128x128 tile, BK=32.
// C[m][n] = sum_k x[m][k]*W[n][k] + bias[n]; head-split [B,H,S,DH] fp16 ws.
// ---------------------------------------------------------------------------
#define GLD 56

__global__ __launch_bounds__(256)
void qkv_gemm(const unsigned short* __restrict__ xh,
              const unsigned short* __restrict__ wh,
              const float* __restrict__ bq,
              const float* __restrict__ bk,
              const float* __restrict__ bv,
              unsigned short* __restrict__ qkv)
{
    const int z = blockIdx.z;
    const unsigned short* W = wh + (size_t)z * ND * ND;
    const float* bias = (z == 0) ? bq : (z == 1) ? bk : bv;
    unsigned short* out = qkv + (size_t)z * NM * ND;

    const int m0 = blockIdx.x * 128;
    const int n0 = blockIdx.y * 128;
    const int tid = threadIdx.x;
    const int lane = tid & 63, wave = tid >> 6;
    const int quad = lane >> 4, l16 = lane & 15;
    const int wm = (wave >> 1) * 64, wn = (wave & 1) * 64;

    __shared__ __align__(16) unsigned short As[128 * GLD];
    __shared__ __align__(16) unsigned short Bs[128 * GLD];

    const f32x4 fz = {0.f, 0.f, 0.f, 0.f};
    f32x4 acc[4][4];
#pragma unroll
    for (int i = 0; i < 4; ++i)
#pragma unroll
        for (int j = 0; j < 4; ++j) acc[i][j] = fz;

    const int srow = tid >> 2;
    const int scb = (tid & 3) * 8;

    for (int kt = 0; kt < ND / 32; ++kt) {
        const int k0 = kt * 32;
        __syncthreads();
#pragma unroll
        for (int i = 0; i < 2; ++i) {
            int row = srow + i * 64;
            *(u16x8*)&As[row * GLD + scb] =
                *(const u16x8*)&xh[(size_t)(m0 + row) * ND + k0 + scb];
            *(u16x8*)&Bs[row * GLD + scb] =
                *(const u16x8*)&W[(size_t)(n0 + row) * ND + k0 + scb];
        }
        __syncthreads();

        f16x8 af[4], bf_[4];
#pragma unroll
        for (int mi = 0; mi < 4; ++mi)
            af[mi] = ldf16x8(&As[(wm + mi * 16 + l16) * GLD + quad * 8]);
#pragma unroll
        for (int ni = 0; ni < 4; ++ni)
            bf_[ni] = ldf16x8(&Bs[(wn + ni * 16 + l16) * GLD + quad * 8]);
#pragma unroll
        for (int mi = 0; mi < 4; ++mi)
#pragma unroll
            for (int ni = 0; ni < 4; ++ni)
                acc[mi][ni] = __builtin_amdgcn_mfma_f32_16x16x32_f16(
                    af[mi], bf_[ni], acc[mi][ni], 0, 0, 0);
    }

#pragma unroll
    for (int ni = 0; ni < 4; ++ni) {
        const int n = n0 + wn + ni * 16 + l16;
        const float bval = bias[n];
        const int hh = n >> 6, d = n & 63;
#pragma unroll
        for (int mi = 0; mi < 4; ++mi) {
#pragma unroll
            for (int r = 0; r < 4; ++r) {
                const int m = m0 + wm + mi * 16 + quad * 4 + r;
                const int bi = m >> 11, s = m & (NS - 1);
                out[(((size_t)(bi * NH + hh)) * NS + s) * NDH + d] =
                    f2h(acc[mi][ni][r] + bval);
            }
        }
    }
}

// ---------------------------------------------------------------------------
// Kernel 2: flash attention via S^T = K Q^T.  P^T lands in B-frag layout of
// mfma_f32_16x16x16f16 -> PV straight from registers (no P LDS round-trip).
// 1 block = 128 Q rows of one (b,h); 32 q/wave; KV tiles of 64.
// ---------------------------------------------------------------------------
#define ALD 72

__global__ __launch_bounds__(256)
void attn_kernel(const unsigned short* __restrict__ qh,
                 const unsigned short* __restrict__ kh,
                 const unsigned short* __restrict__ vh,
                 float* __restrict__ out)             // fp32 out
{
    const int bh = blockIdx.y;
    const int bb = bh / NH, hh = bh % NH;
    const int tid = threadIdx.x;
    const int lane = tid & 63, wave = tid >> 6;
    const int quad = lane >> 4, l16 = lane & 15;
    const int q0 = blockIdx.x * 128 + wave * 32;

    __shared__ __align__(16) unsigned short Ks[64 * ALD];
    __shared__ __align__(16) unsigned short VTs[64 * ALD];   // [d][kv]

    const unsigned short* qb = qh + (size_t)bh * NS * NDH;
    const unsigned short* kb = kh + (size_t)bh * NS * NDH;
    const unsigned short* vb = vh + (size_t)bh * NS * NDH;

    // Q B-frags (for S^T): B[n=q(l16)][k=dh(quad*8+j)] per K=32 chunk
    f16x8 bq_[2][2];
#pragma unroll
    for (int qt = 0; qt < 2; ++qt)
#pragma unroll
        for (int kk = 0; kk < 2; ++kk)
            bq_[qt][kk] = ldf16x8(
                &qb[(size_t)(q0 + qt * 16 + l16) * NDH + kk * 32 + quad * 8]);

    const float c2 = 0.18033688011112042f;  // log2(e) / sqrt(64)

    const f32x4 fz = {0.f, 0.f, 0.f, 0.f};
    // O^T accumulators: o[qt][dt], C-layout col=q(l16), row=d(quad*4+r)
    f32x4 o[2][4];
    float m2[2], lsum[2];
#pragma unroll
    for (int qt = 0; qt < 2; ++qt) {
#pragma unroll
        for (int dt = 0; dt < 4; ++dt) o[qt][dt] = fz;
        m2[qt] = -__builtin_inff();
        lsum[qt] = 0.f;
    }

    const int kcb = (tid & 7) * 8;

    for (int kt = 0; kt < NS / 64; ++kt) {
        const int kv0 = kt * 64;
        __syncthreads();
        // stage K row-major [kv][dh]
#pragma unroll
        for (int i = 0; i < 2; ++i) {
            int row = (tid >> 3) + i * 32;
            *(u16x8*)&Ks[row * ALD + kcb] =
                *(const u16x8*)&kb[(size_t)(kv0 + row) * NDH + kcb];
        }
        // stage V transposed [d][kv]
#pragma unroll
        for (int i = 0; i < 2; ++i) {
            const int vrow = lane;
            const int cb = (wave + i * 4) * 8;
            u16x8 vv = *(const u16x8*)&vb[(size_t)(kv0 + vrow) * NDH + cb];
#pragma unroll
            for (int j = 0; j < 8; ++j)
                VTs[(cb + j) * ALD + vrow] = vv[j];
        }
        __syncthreads();

        // K A-frags: A[m=kv(l16)][k=dh(quad*8+j)]
        f16x8 ak[4][2];
#pragma unroll
        for (int kvt = 0; kvt < 4; ++kvt)
#pragma unroll
            for (int kk = 0; kk < 2; ++kk)
                ak[kvt][kk] = ldf16x8(&Ks[(kvt * 16 + l16) * ALD + kk * 32 + quad * 8]);

        // S^T[kv][q] = K · Q^T
        f32x4 st[2][4];
#pragma unroll
        for (int qt = 0; qt < 2; ++qt)
#pragma unroll
            for (int kvt = 0; kvt < 4; ++kvt) {
                st[qt][kvt] = fz;
#pragma unroll
                for (int kk = 0; kk < 2; ++kk)
                    st[qt][kvt] = __builtin_amdgcn_mfma_f32_16x16x32_f16(
                        ak[kvt][kk], bq_[qt][kk], st[qt][kvt], 0, 0, 0);
            }

        // V^T A-frags for PV (K=16): A[m=d(l16)][k=kv(quad*4+j)]
        f16x4 av[4][4];
#pragma unroll
        for (int dt = 0; dt < 4; ++dt)
#pragma unroll
            for (int kvt = 0; kvt < 4; ++kvt)
                av[dt][kvt] = ldf16x4(&VTs[(dt * 16 + l16) * ALD + kvt * 16 + quad * 4]);

        // online softmax over kv (rows of S^T): per-lane 16 values, then
        // reduce across quads (xor 16, 32)
#pragma unroll
        for (int qt = 0; qt < 2; ++qt) {
            float rm = st[qt][0][0];
#pragma unroll
            for (int kvt = 0; kvt < 4; ++kvt)
#pragma unroll
                for (int r = 0; r < 4; ++r)
                    rm = fmaxf(rm, st[qt][kvt][r]);
            rm = fmaxf(rm, __shfl_xor(rm, 16, 64));
            rm = fmaxf(rm, __shfl_xor(rm, 32, 64));

            const float mn = fmaxf(m2[qt], rm * c2);
            const float al = exp2f(m2[qt] - mn);
            m2[qt] = mn;

            float p[4][4];
            float rs = 0.f;
#pragma unroll
            for (int kvt = 0; kvt < 4; ++kvt)
#pragma unroll
                for (int r = 0; r < 4; ++r) {
                    p[kvt][r] = exp2f(fmaf(st[qt][kvt][r], c2, -mn));
                    rs += p[kvt][r];
                }
            rs += __shfl_xor(rs, 16, 64);
            rs += __shfl_xor(rs, 32, 64);
            lsum[qt] = lsum[qt] * al + rs;

#pragma unroll
            for (int dt = 0; dt < 4; ++dt)
                o[qt][dt] *= al;

            // P^T is already in B-frag layout for 16x16x16: B[n=q(l16)][k=quad*4+r]
            f16x4 pf[4];
#pragma unroll
            for (int kvt = 0; kvt < 4; ++kvt) {
#pragma unroll
                for (int r = 0; r < 4; ++r)
                    pf[kvt][r] = (_Float16)p[kvt][r];
            }

            // O^T += V^T · P^T
#pragma unroll
            for (int dt = 0; dt < 4; ++dt)
#pragma unroll
                for (int kvt = 0; kvt < 4; ++kvt)
                    o[qt][dt] = __builtin_amdgcn_mfma_f32_16x16x16f16(
                        av[dt][kvt], pf[kvt], o[qt][dt], 0, 0, 0);
        }
    }

    // epilogue: O^T C-layout -> out[B,S,H*DH] fp32, float4 per (qt,dt)
#pragma unroll
    for (int qt = 0; qt < 2; ++qt) {
        const int q = q0 + qt * 16 + l16;
        const float inv = 1.f / lsum[qt];
#pragma unroll
        for (int dt = 0; dt < 4; ++dt) {
            float4 v;
            v.x = o[qt][dt][0] * inv;
            v.y = o[qt][dt][1] * inv;
            v.z = o[qt][dt][2] * inv;
            v.w = o[qt][dt][3] * inv;
            *(float4*)&out[((size_t)(bb * NS + q)) * ND + hh * NDH + dt * 16 + quad * 4] = v;
        }
    }
}

// ---------------------------------------------------------------------------
extern "C" void kernel_launch(void* const* d_in, const int* in_sizes, int n_in,
                              void* d_out, int out_size, void* d_ws, size_t ws_size,
                              hipStream_t stream)
{
    const float* x  = (const float*)d_in[0];
    const float* Wq = (const float*)d_in[1];
    const float* bq = (const float*)d_in[2];
    const float* Wk = (const float*)d_in[3];
    const float* bk = (const float*)d_in[4];
    const float* Wv = (const float*)d_in[5];
    const float* bv = (const float*)d_in[6];

    unsigned short* ws  = (unsigned short*)d_ws;
    unsigned short* xh  = ws;                          // NM*ND f16
    unsigned short* wh  = xh + (size_t)NM * ND;        // 3*ND*ND f16
    unsigned short* qkv = wh + (size_t)3 * ND * ND;    // 3*NM*ND f16
    unsigned short* qhp = qkv;
    unsigned short* khp = qkv + (size_t)NM * ND;
    unsigned short* vhp = qkv + (size_t)2 * NM * ND;

    const int convBlocks = (NM * ND + 3 * ND * ND) / (8 * 256);  // 3936
    conv_f32_to_f16<<<convBlocks, 256, 0, stream>>>(x, Wq, Wk, Wv, xh);

    qkv_gemm<<<dim3(NM / 128, ND / 128, 3), 256, 0, stream>>>(
        xh, wh, bq, bk, bv, qkv);

    attn_kernel<<<dim3(NS / 128, NB * NH), 256, 0, stream>>>(
        qhp, khp, vhp, (float*)d_out);
}

// Round 10
// 248.781 us; speedup vs baseline: 7.9021x; 1.1342x over previous
//
#include <hip/hip_runtime.h>

#define NB 4
#define NS 2048
#define ND 768
#define NH 12
#define NDH 64
#define NM (NB * NS)   // 8192

typedef __attribute__((ext_vector_type(8))) _Float16 f16x8;
typedef __attribute__((ext_vector_type(4))) _Float16 f16x4;
typedef __attribute__((ext_vector_type(8))) unsigned short u16x8;
typedef __attribute__((ext_vector_type(4))) unsigned short u16x4;
typedef __attribute__((ext_vector_type(4))) float f32x4;

__device__ __forceinline__ unsigned short f2h(float f) {
    _Float16 h = (_Float16)f;
    return __builtin_bit_cast(unsigned short, h);
}
__device__ __forceinline__ f16x8 ldf16x8(const unsigned short* p) {
    return __builtin_bit_cast(f16x8, *(const u16x8*)p);
}
__device__ __forceinline__ f16x4 ldf16x4(const unsigned short* p) {
    return __builtin_bit_cast(f16x4, *(const u16x4*)p);
}
__device__ __forceinline__ void gload_lds16(const void* g, void* l) {
    __builtin_amdgcn_global_load_lds(
        (const __attribute__((address_space(1))) void*)g,
        (__attribute__((address_space(3))) void*)l, 16, 0, 0);
}

// ---------------------------------------------------------------------------
// Kernel 0: fp32 -> fp16 conversion of x, Wq, Wk, Wv into ws (xh | wh[3])
// ---------------------------------------------------------------------------
__global__ __launch_bounds__(256)
void conv_f32_to_f16(const float* __restrict__ x,
                     const float* __restrict__ wq,
                     const float* __restrict__ wk,
                     const float* __restrict__ wv,
                     unsigned short* __restrict__ dst)
{
    const int CX = (NM * ND) / 8;
    const int CW = (ND * ND) / 8;
    int c = blockIdx.x * 256 + threadIdx.x;
    const float* src;
    int base;
    if (c < CX)               { src = x;  base = 0; }
    else if (c < CX + CW)     { src = wq; base = CX; }
    else if (c < CX + 2 * CW) { src = wk; base = CX + CW; }
    else                      { src = wv; base = CX + 2 * CW; }
    const float4* p = (const float4*)&src[(size_t)(c - base) * 8];
    float4 a = p[0], b = p[1];
    u16x8 r;
    r[0] = f2h(a.x); r[1] = f2h(a.y); r[2] = f2h(a.z); r[3] = f2h(a.w);
    r[4] = f2h(b.x); r[5] = f2h(b.y); r[6] = f2h(b.z); r[7] = f2h(b.w);
    *(u16x8*)&dst[(size_t)c * 8] = r;
}

// ---------------------------------------------------------------------------
// Kernel 1: QKV GEMM, m97 structure: unpadded 128x32 f16 LDS tiles staged via
// global_load_lds width=16.  128x128 tile, BK=32, 4 waves, 16x16x32 MFMA.
// LDS layout [row][32] unpadded: lane L of a 1KB issue lands at seg*512+L*8,
// which equals row-major (seg*16 + L/4)*32 + (L%4)*8.  (m97-verified pattern)
// ---------------------------------------------------------------------------
__global__ __launch_bounds__(256)
void qkv_gemm(const unsigned short* __restrict__ xh,
              const unsigned short* __restrict__ wh,
              const float* __restrict__ bq,
              const float* __restrict__ bk,
              const float* __restrict__ bv,
              unsigned short* __restrict__ qkv)
{
    const int z = blockIdx.z;
    const unsigned short* W = wh + (size_t)z * ND * ND;
    const float* bias = (z == 0) ? bq : (z == 1) ? bk : bv;
    unsigned short* out = qkv + (size_t)z * NM * ND;

    const int m0 = blockIdx.x * 128;
    const int n0 = blockIdx.y * 128;
    const int tid = threadIdx.x;
    const int lane = tid & 63, wave = tid >> 6;
    const int quad = lane >> 4, l16 = lane & 15;
    const int wm = (wave >> 1) * 64, wn = (wave & 1) * 64;

    __shared__ __align__(16) unsigned short As[128 * 32];
    __shared__ __align__(16) unsigned short Bs[128 * 32];

    const f32x4 fz = {0.f, 0.f, 0.f, 0.f};
    f32x4 acc[4][4];
#pragma unroll
    for (int i = 0; i < 4; ++i)
#pragma unroll
        for (int j = 0; j < 4; ++j) acc[i][j] = fz;

    // staging geometry: seg in 0..7 (16 rows each); lane L covers
    // row seg*16 + L/4, k-elems (L%4)*8 .. +7  (16B)
    const int lrow = lane >> 2;          // 0..15
    const int lcol = (lane & 3) * 8;     // 0,8,16,24

    for (int kt = 0; kt < ND / 32; ++kt) {
        const int k0 = kt * 32;
        __syncthreads();
#pragma unroll
        for (int i = 0; i < 2; ++i) {
            const int seg = wave * 2 + i;        // 0..7
            const int row = seg * 16 + lrow;
            gload_lds16(&xh[(size_t)(m0 + row) * ND + k0 + lcol], &As[seg * 512]);
            gload_lds16(&W[(size_t)(n0 + row) * ND + k0 + lcol], &Bs[seg * 512]);
        }
        __syncthreads();   // compiler emits vmcnt(0) drain here (m97 structure)

        f16x8 af[4], bf_[4];
#pragma unroll
        for (int mi = 0; mi < 4; ++mi)
            af[mi] = ldf16x8(&As[(wm + mi * 16 + l16) * 32 + quad * 8]);
#pragma unroll
        for (int ni = 0; ni < 4; ++ni)
            bf_[ni] = ldf16x8(&Bs[(wn + ni * 16 + l16) * 32 + quad * 8]);
#pragma unroll
        for (int mi = 0; mi < 4; ++mi)
#pragma unroll
            for (int ni = 0; ni < 4; ++ni)
                acc[mi][ni] = __builtin_amdgcn_mfma_f32_16x16x32_f16(
                    af[mi], bf_[ni], acc[mi][ni], 0, 0, 0);
    }

#pragma unroll
    for (int ni = 0; ni < 4; ++ni) {
        const int n = n0 + wn + ni * 16 + l16;
        const float bval = bias[n];
        const int hh = n >> 6, d = n & 63;
#pragma unroll
        for (int mi = 0; mi < 4; ++mi) {
#pragma unroll
            for (int r = 0; r < 4; ++r) {
                const int m = m0 + wm + mi * 16 + quad * 4 + r;
                const int bi = m >> 11, s = m & (NS - 1);
                out[(((size_t)(bi * NH + hh)) * NS + s) * NDH + d] =
                    f2h(acc[mi][ni][r] + bval);
            }
        }
    }
}

// ---------------------------------------------------------------------------
// Kernel 2: flash attention via S^T = K Q^T (R9-proven layouts).
// New: 128 KV staged per barrier-pair (2 compute sub-tiles), register
// prefetch of tile t+1 overlapping compute of tile t, paired-b32 V staging.
// ---------------------------------------------------------------------------
#define ALD 72    // Ks row stride (16B-aligned rows)
#define KLD 136   // VTs row stride: 128 kv + 8 pad

__global__ __launch_bounds__(256)
void attn_kernel(const unsigned short* __restrict__ qh,
                 const unsigned short* __restrict__ kh,
                 const unsigned short* __restrict__ vh,
                 float* __restrict__ out)
{
    const int bh = blockIdx.y;
    const int bb = bh / NH, hh = bh % NH;
    const int tid = threadIdx.x;
    const int lane = tid & 63, wave = tid >> 6;
    const int quad = lane >> 4, l16 = lane & 15;
    const int q0 = blockIdx.x * 128 + wave * 32;

    __shared__ __align__(16) unsigned short Ks[128 * ALD];   // [kv][dh]
    __shared__ __align__(16) unsigned short VTs[64 * KLD];   // [d][kv]

    const unsigned short* qb = qh + (size_t)bh * NS * NDH;
    const unsigned short* kb = kh + (size_t)bh * NS * NDH;
    const unsigned short* vb = vh + (size_t)bh * NS * NDH;

    // Q B-frags: B[n=q(l16)][k=dh(quad*8+j)]
    f16x8 bq_[2][2];
#pragma unroll
    for (int qt = 0; qt < 2; ++qt)
#pragma unroll
        for (int kk = 0; kk < 2; ++kk)
            bq_[qt][kk] = ldf16x8(
                &qb[(size_t)(q0 + qt * 16 + l16) * NDH + kk * 32 + quad * 8]);

    const float c2 = 0.18033688011112042f;  // log2(e) / sqrt(64)

    const f32x4 fz = {0.f, 0.f, 0.f, 0.f};
    f32x4 o[2][4];
    float m2[2], lsum[2];
#pragma unroll
    for (int qt = 0; qt < 2; ++qt) {
#pragma unroll
        for (int dt = 0; dt < 4; ++dt) o[qt][dt] = fz;
        m2[qt] = -__builtin_inff();
        lsum[qt] = 0.f;
    }

    // staging geometry
    const int krow = tid >> 3;            // 0..31 (K rows +i*32)
    const int kcol = (tid & 7) * 8;       // dh chunk
    const int vpair = tid & 31;           // kv pair (+i2*32)
    const int vchunk = tid >> 5;          // 0..7 (d chunk)

    // prefetch registers (tile t+1 loads overlap tile t compute)
    u16x8 kr[4], vr0[2], vr1[2];
#pragma unroll
    for (int i = 0; i < 4; ++i)
        kr[i] = *(const u16x8*)&kb[(size_t)(krow + i * 32) * NDH + kcol];
#pragma unroll
    for (int i2 = 0; i2 < 2; ++i2) {
        const int P = vpair + i2 * 32;
        vr0[i2] = *(const u16x8*)&vb[(size_t)(2 * P) * NDH + vchunk * 8];
        vr1[i2] = *(const u16x8*)&vb[(size_t)(2 * P + 1) * NDH + vchunk * 8];
    }

    for (int kt = 0; kt < NS / 128; ++kt) {
        __syncthreads();   // previous tile's LDS consumers done
        // ---- write staged tile to LDS ----
#pragma unroll
        for (int i = 0; i < 4; ++i)
            *(u16x8*)&Ks[(krow + i * 32) * ALD + kcol] = kr[i];
#pragma unroll
        for (int i2 = 0; i2 < 2; ++i2) {
            const int P = vpair + i2 * 32;
#pragma unroll
            for (int j = 0; j < 8; ++j) {
                unsigned pk = (unsigned)vr0[i2][j] | ((unsigned)vr1[i2][j] << 16);
                *(unsigned*)&VTs[(vchunk * 8 + j) * KLD + 2 * P] = pk;
            }
        }
        // ---- prefetch next tile (in flight during compute) ----
        if (kt + 1 < NS / 128) {
            const int kv1 = (kt + 1) * 128;
#pragma unroll
            for (int i = 0; i < 4; ++i)
                kr[i] = *(const u16x8*)&kb[(size_t)(kv1 + krow + i * 32) * NDH + kcol];
#pragma unroll
            for (int i2 = 0; i2 < 2; ++i2) {
                const int P = vpair + i2 * 32;
                vr0[i2] = *(const u16x8*)&vb[(size_t)(kv1 + 2 * P) * NDH + vchunk * 8];
                vr1[i2] = *(const u16x8*)&vb[(size_t)(kv1 + 2 * P + 1) * NDH + vchunk * 8];
            }
        }
        __syncthreads();   // staged tile visible

        // ---- two 64-kv compute sub-tiles ----
#pragma unroll
        for (int half = 0; half < 2; ++half) {
            const int kvb = half * 64;

            // K A-frags: A[m=kv(l16)][k=dh(quad*8+j)]
            f16x8 ak[4][2];
#pragma unroll
            for (int kvt = 0; kvt < 4; ++kvt)
#pragma unroll
                for (int kk = 0; kk < 2; ++kk)
                    ak[kvt][kk] = ldf16x8(
                        &Ks[(kvb + kvt * 16 + l16) * ALD + kk * 32 + quad * 8]);

            // S^T = K · Q^T
            f32x4 st[2][4];
#pragma unroll
            for (int qt = 0; qt < 2; ++qt)
#pragma unroll
                for (int kvt = 0; kvt < 4; ++kvt) {
                    st[qt][kvt] = fz;
#pragma unroll
                    for (int kk = 0; kk < 2; ++kk)
                        st[qt][kvt] = __builtin_amdgcn_mfma_f32_16x16x32_f16(
                            ak[kvt][kk], bq_[qt][kk], st[qt][kvt], 0, 0, 0);
                }

            // V^T A-frags: A[m=d(l16)][k=kv(quad*4+j)]
            f16x4 av[4][4];
#pragma unroll
            for (int dt = 0; dt < 4; ++dt)
#pragma unroll
                for (int kvt = 0; kvt < 4; ++kvt)
                    av[dt][kvt] = ldf16x4(
                        &VTs[(dt * 16 + l16) * KLD + kvb + kvt * 16 + quad * 4]);

            // online softmax + PV
#pragma unroll
            for (int qt = 0; qt < 2; ++qt) {
                float rm = st[qt][0][0];
#pragma unroll
                for (int kvt = 0; kvt < 4; ++kvt)
#pragma unroll
                    for (int r = 0; r < 4; ++r)
                        rm = fmaxf(rm, st[qt][kvt][r]);
                rm = fmaxf(rm, __shfl_xor(rm, 16, 64));
                rm = fmaxf(rm, __shfl_xor(rm, 32, 64));

                const float mn = fmaxf(m2[qt], rm * c2);
                const float al = exp2f(m2[qt] - mn);
                m2[qt] = mn;

                float p[4][4];
                float rs = 0.f;
#pragma unroll
                for (int kvt = 0; kvt < 4; ++kvt)
#pragma unroll
                    for (int r = 0; r < 4; ++r) {
                        p[kvt][r] = exp2f(fmaf(st[qt][kvt][r], c2, -mn));
                        rs += p[kvt][r];
                    }
                rs += __shfl_xor(rs, 16, 64);
                rs += __shfl_xor(rs, 32, 64);
                lsum[qt] = lsum[qt] * al + rs;

#pragma unroll
                for (int dt = 0; dt < 4; ++dt)
                    o[qt][dt] *= al;

                // P^T already in B-frag layout for 16x16x16
                f16x4 pf[4];
#pragma unroll
                for (int kvt = 0; kvt < 4; ++kvt)
#pragma unroll
                    for (int r = 0; r < 4; ++r)
                        pf[kvt][r] = (_Float16)p[kvt][r];

#pragma unroll
                for (int dt = 0; dt < 4; ++dt)
#pragma unroll
                    for (int kvt = 0; kvt < 4; ++kvt)
                        o[qt][dt] = __builtin_amdgcn_mfma_f32_16x16x16f16(
                            av[dt][kvt], pf[kvt], o[qt][dt], 0, 0, 0);
            }
        }
    }

    // epilogue: O^T C-layout -> out[B,S,H*DH] fp32
#pragma unroll
    for (int qt = 0; qt < 2; ++qt) {
        const int q = q0 + qt * 16 + l16;
        const float inv = 1.f / lsum[qt];
#pragma unroll
        for (int dt = 0; dt < 4; ++dt) {
            float4 v;
            v.x = o[qt][dt][0] * inv;
            v.y = o[qt][dt][1] * inv;
            v.z = o[qt][dt][2] * inv;
            v.w = o[qt][dt][3] * inv;
            *(float4*)&out[((size_t)(bb * NS + q)) * ND + hh * NDH + dt * 16 + quad * 4] = v;
        }
    }
}

// ---------------------------------------------------------------------------
extern "C" void kernel_launch(void* const* d_in, const int* in_sizes, int n_in,
                              void* d_out, int out_size, void* d_ws, size_t ws_size,
                              hipStream_t stream)
{
    const float* x  = (const float*)d_in[0];
    const float* Wq = (const float*)d_in[1];
    const float* bq = (const float*)d_in[2];
    const float* Wk = (const float*)d_in[3];
    const float* bk = (const float*)d_in[4];
    const float* Wv = (const float*)d_in[5];
    const float* bv = (const float*)d_in[6];

    unsigned short* ws  = (unsigned short*)d_ws;
    unsigned short* xh  = ws;                          // NM*ND f16
    unsigned short* wh  = xh + (size_t)NM * ND;        // 3*ND*ND f16
    unsigned short* qkv = wh + (size_t)3 * ND * ND;    // 3*NM*ND f16
    unsigned short* qhp = qkv;
    unsigned short* khp = qkv + (size_t)NM * ND;
    unsigned short* vhp = qkv + (size_t)2 * NM * ND;

    const int convBlocks = (NM * ND + 3 * ND * ND) / (8 * 256);
    conv_f32_to_f16<<<convBlocks, 256, 0, stream>>>(x, Wq, Wk, Wv, xh);

    qkv_gemm<<<dim3(NM / 128, ND / 128, 3), 256, 0, stream>>>(
        xh, wh, bq, bk, bv, qkv);

    attn_kernel<<<dim3(NS / 128, NB * NH), 256, 0, stream>>>(
        qhp, khp, vhp, (float*)d_out);
}